// Round 1
// baseline (3621.336 us; speedup 1.0000x reference)
//
#include <hip/hip_runtime.h>
#include <math.h>

static inline int cdiv(int a, int b) { return (a + b - 1) / b; }

// ---------------- CSR build ----------------
__global__ void k_count(const int* __restrict__ dst, int E, int* __restrict__ cnt) {
  int i = blockIdx.x * 256 + threadIdx.x;
  if (i < E) atomicAdd(&cnt[dst[i]], 1);
}

// exclusive scan within chunks of 1024; sums[b] = chunk total
__global__ __launch_bounds__(256) void k_scan_chunk(const int* __restrict__ in, int n,
                                                    int* __restrict__ out, int* __restrict__ sums) {
  __shared__ int tsum[256];
  int base = blockIdx.x * 1024;
  int t = threadIdx.x;
  int v[4]; int s = 0;
#pragma unroll
  for (int i = 0; i < 4; i++) { int idx = base + t * 4 + i; int x = (idx < n) ? in[idx] : 0; v[i] = x; s += x; }
  tsum[t] = s;
  __syncthreads();
  int x = s;
  for (int off = 1; off < 256; off <<= 1) {
    int y = (t >= off) ? tsum[t - off] : 0;
    __syncthreads();
    x += y;
    tsum[t] = x;
    __syncthreads();
  }
  int run = x - s;
#pragma unroll
  for (int i = 0; i < 4; i++) { int idx = base + t * 4 + i; if (idx < n) out[idx] = run; run += v[i]; }
  if (t == 255 && sums) sums[blockIdx.x] = x;
}

__global__ void k_scan_add(int* __restrict__ out, int n, const int* __restrict__ se,
                           int total, int* __restrict__ cur) {
  int i = blockIdx.x * 256 + threadIdx.x;
  if (i < n) { int v = out[i] + se[i >> 10]; out[i] = v; cur[i] = v; }
  if (i == 0) out[n] = total;
}

__global__ void k_fill(const int* __restrict__ src, const int* __restrict__ dst, int E,
                       int* __restrict__ cur, int* __restrict__ adj) {
  int i = blockIdx.x * 256 + threadIdx.x;
  if (i < E) { int p = atomicAdd(&cur[dst[i]], 1); adj[p] = src[i]; }
}

// ---------------- GAT1 attention-logit projections ----------------
// Vs[k*10+h] = sum_c W1[k,h*78+c]*a_src1[h,c]  (so al = x @ Vs)
__global__ void k_vsrc(const float* __restrict__ W1, const float* __restrict__ a_src,
                       const float* __restrict__ a_dst, float* __restrict__ Vs, float* __restrict__ Vd) {
  int t = blockIdx.x * 64 + threadIdx.x;
  if (t >= 780) return;
  int k = t / 10, h = t % 10;
  float ss = 0.f, sd = 0.f;
  for (int c = 0; c < 78; c++) {
    float w = W1[k * 780 + h * 78 + c];
    ss += w * a_src[h * 78 + c];
    sd += w * a_dst[h * 78 + c];
  }
  Vs[k * 10 + h] = ss; Vd[k * 10 + h] = sd;
}

__global__ void k_alar1(const float* __restrict__ x, const float* __restrict__ Vs,
                        const float* __restrict__ Vd, float* __restrict__ al,
                        float* __restrict__ ar, int nd) {
  int t = blockIdx.x * 256 + threadIdx.x;
  if (t >= nd * 10) return;
  int n = t / 10, h = t % 10;
  const float* xr = x + (size_t)n * 78;
  float sa = 0.f, sd = 0.f;
  for (int k = 0; k < 78; k++) { float xv = xr[k]; sa += xv * Vs[k * 10 + h]; sd += xv * Vd[k * 10 + h]; }
  al[t] = sa; ar[t] = sd;
}

// ---------------- GAT1 aggregation: z[dst,h,k] = sum_e alpha[e,h] * x[src_e,k] ----------------
__global__ __launch_bounds__(64) void k_gat_agg1(const float* __restrict__ x, const int* __restrict__ adj,
                                                 const int* __restrict__ roff, const float* __restrict__ al,
                                                 const float* __restrict__ ar, float* __restrict__ z, int node0) {
  int n = node0 + blockIdx.x;
  int lane = threadIdx.x;
  int rs = roff[n];
  int deg = roff[n + 1] - rs;   // real in-edges; +1 virtual self loop at index deg
  int tot = deg + 1;
  __shared__ float m_s[10], is_s[10], ar_s[10];
  __shared__ float red_s[64];
  __shared__ int src_s[64];
  __shared__ float alpha_s[64][10];
  if (lane < 10) ar_s[lane] = ar[n * 10 + lane];
  __syncthreads();
  int h = lane % 10; int eL = lane / 10;   // lanes 0..59: 6 edge-groups x 10 heads
  // phase 1: per-head max
  float mx = -1e30f;
  if (lane < 60) {
    for (int e = eL; e < tot; e += 6) {
      int s = (e == deg) ? n : adj[rs + e];
      float v = al[s * 10 + h] + ar_s[h];
      v = (v >= 0.f) ? v : 0.2f * v;
      mx = fmaxf(mx, v);
    }
  }
  red_s[lane] = mx;
  __syncthreads();
  if (lane < 10) {
    float m = red_s[lane];
    for (int g = 1; g < 6; g++) m = fmaxf(m, red_s[lane + g * 10]);
    m_s[lane] = m;
  }
  __syncthreads();
  // phase 2: per-head sum of exp
  float sm = 0.f;
  if (lane < 60) {
    float m = m_s[h];
    for (int e = eL; e < tot; e += 6) {
      int s = (e == deg) ? n : adj[rs + e];
      float v = al[s * 10 + h] + ar_s[h];
      v = (v >= 0.f) ? v : 0.2f * v;
      sm += __expf(v - m);
    }
  }
  red_s[lane] = sm;
  __syncthreads();
  if (lane < 10) {
    float s = 0.f;
    for (int g = 0; g < 6; g++) s += red_s[lane + g * 10];
    is_s[lane] = 1.f / (s + 1e-16f);
  }
  __syncthreads();
  // phase 3: chunked alpha + aggregation. lane owns channel c=lane and c=64+lane (lane<14)
  float zA[10], zB[10];
#pragma unroll
  for (int i = 0; i < 10; i++) { zA[i] = 0.f; zB[i] = 0.f; }
  for (int c0 = 0; c0 < tot; c0 += 64) {
    int csz = (tot - c0 < 64) ? (tot - c0) : 64;
    if (lane < csz) {
      int e = c0 + lane;
      src_s[lane] = (e == deg) ? n : adj[rs + e];
    }
    __syncthreads();
    for (int p = lane; p < csz * 10; p += 64) {
      int e = p / 10; int hh = p % 10;
      int s = src_s[e];
      float v = al[s * 10 + hh] + ar_s[hh];
      v = (v >= 0.f) ? v : 0.2f * v;
      alpha_s[e][hh] = __expf(v - m_s[hh]) * is_s[hh];
    }
    __syncthreads();
    for (int e = 0; e < csz; e++) {
      int s = src_s[e];
      float xa = x[(size_t)s * 78 + lane];
      float xb = (lane < 14) ? x[(size_t)s * 78 + 64 + lane] : 0.f;
#pragma unroll
      for (int hh = 0; hh < 10; hh++) {
        float a = alpha_s[e][hh];
        zA[hh] += a * xa;
        zB[hh] += a * xb;
      }
    }
    __syncthreads();
  }
  float* zr = z + (size_t)blockIdx.x * 780;
#pragma unroll
  for (int hh = 0; hh < 10; hh++) {
    zr[hh * 78 + lane] = zA[hh];
    if (lane < 14) zr[hh * 78 + 64 + lane] = zB[hh];
  }
}

// ---------------- generic f32 GEMM: C = act(A@B + bias) ----------------
// BM=64,BN=64,BK=16, 256 threads, 4x4 micro-tile. ACT: 0 none, 1 relu, 2 elu
template <int ACT>
__global__ __launch_bounds__(256) void k_gemm(const float* __restrict__ A, const float* __restrict__ B,
                                              const float* __restrict__ bias, float* __restrict__ C,
                                              int M, int N, int K, int lda, int ldb, int ldc) {
  __shared__ float As[16][68];
  __shared__ float Bs[16][68];
  int tx = threadIdx.x % 16, ty = threadIdx.x / 16;
  int bm = blockIdx.x * 64, bn = blockIdx.y * 64;
  float acc[4][4] = {};
  for (int k0 = 0; k0 < K; k0 += 16) {
    for (int i = threadIdx.x; i < 1024; i += 256) {
      int r = i / 16, kk = i % 16;
      int gm = bm + r, gk = k0 + kk;
      As[kk][r] = (gm < M && gk < K) ? A[(size_t)gm * lda + gk] : 0.f;
    }
    for (int i = threadIdx.x; i < 1024; i += 256) {
      int kk = i / 64, c = i % 64;
      int gk = k0 + kk, gn = bn + c;
      Bs[kk][c] = (gk < K && gn < N) ? B[(size_t)gk * ldb + gn] : 0.f;
    }
    __syncthreads();
#pragma unroll
    for (int kk = 0; kk < 16; kk++) {
      float a[4], b[4];
#pragma unroll
      for (int i = 0; i < 4; i++) a[i] = As[kk][ty * 4 + i];
#pragma unroll
      for (int j = 0; j < 4; j++) b[j] = Bs[kk][tx * 4 + j];
#pragma unroll
      for (int i = 0; i < 4; i++)
#pragma unroll
        for (int j = 0; j < 4; j++) acc[i][j] += a[i] * b[j];
    }
    __syncthreads();
  }
#pragma unroll
  for (int i = 0; i < 4; i++) {
    int gm = bm + ty * 4 + i;
    if (gm >= M) continue;
#pragma unroll
    for (int j = 0; j < 4; j++) {
      int gn = bn + tx * 4 + j;
      if (gn >= N) continue;
      float v = acc[i][j] + (bias ? bias[gn] : 0.f);
      if (ACT == 1) v = fmaxf(v, 0.f);
      else if (ACT == 2) v = (v > 0.f) ? v : (__expf(v) - 1.f);
      C[(size_t)gm * ldc + gn] = v;
    }
  }
}

// ---------------- GAT2 ----------------
__global__ __launch_bounds__(64) void k_alar2(const float* __restrict__ h2, const float* __restrict__ a_src,
                                              const float* __restrict__ a_dst, float* __restrict__ al,
                                              float* __restrict__ ar) {
  int n = blockIdx.x, lane = threadIdx.x;
  float v0 = h2[(size_t)n * 128 + lane], v1 = h2[(size_t)n * 128 + 64 + lane];
  float sa = v0 * a_src[lane] + v1 * a_src[64 + lane];
  float sd = v0 * a_dst[lane] + v1 * a_dst[64 + lane];
#pragma unroll
  for (int o = 32; o; o >>= 1) { sa += __shfl_xor(sa, o); sd += __shfl_xor(sd, o); }
  if (lane == 0) { al[n] = sa; ar[n] = sd; }
}

__global__ __launch_bounds__(64) void k_gat_agg2(const float* __restrict__ h2, const int* __restrict__ adj,
                                                 const int* __restrict__ roff, const float* __restrict__ al,
                                                 const float* __restrict__ ar, const float* __restrict__ b2,
                                                 float* __restrict__ out) {
  int n = blockIdx.x, lane = threadIdx.x;
  int rs = roff[n];
  int deg = roff[n + 1] - rs;
  int tot = deg + 1;
  float arn = ar[n];
  float mx = -1e30f;
  for (int e = lane; e < tot; e += 64) {
    int s = (e == deg) ? n : adj[rs + e];
    float v = al[s] + arn; v = (v >= 0.f) ? v : 0.2f * v;
    mx = fmaxf(mx, v);
  }
#pragma unroll
  for (int o = 32; o; o >>= 1) mx = fmaxf(mx, __shfl_xor(mx, o));
  float sm = 0.f;
  for (int e = lane; e < tot; e += 64) {
    int s = (e == deg) ? n : adj[rs + e];
    float v = al[s] + arn; v = (v >= 0.f) ? v : 0.2f * v;
    sm += __expf(v - mx);
  }
#pragma unroll
  for (int o = 32; o; o >>= 1) sm += __shfl_xor(sm, o);
  float inv = 1.f / (sm + 1e-16f);
  float a0 = 0.f, a1 = 0.f;
  for (int e = 0; e < tot; e++) {
    int s = (e == deg) ? n : adj[rs + e];
    float v = al[s] + arn; v = (v >= 0.f) ? v : 0.2f * v;
    float alpha = __expf(v - mx) * inv;
    a0 += alpha * h2[(size_t)s * 128 + lane];
    a1 += alpha * h2[(size_t)s * 128 + 64 + lane];
  }
  out[(size_t)n * 128 + lane]      = fmaxf(a0 + b2[lane], 0.f);
  out[(size_t)n * 128 + 64 + lane] = fmaxf(a1 + b2[64 + lane], 0.f);
}

// ---------------- GCN ----------------
__global__ void k_dis(const int* __restrict__ roff, float* __restrict__ dis, int n) {
  int i = blockIdx.x * 256 + threadIdx.x;
  if (i < n) dis[i] = rsqrtf((float)(roff[i + 1] - roff[i] + 1));
}

__global__ __launch_bounds__(64) void k_gcn_agg(const float* __restrict__ h, const int* __restrict__ adj,
                                                const int* __restrict__ roff, const float* __restrict__ dis,
                                                const float* __restrict__ bias, float* __restrict__ out, int C) {
  int n = blockIdx.x, lane = threadIdx.x;
  int rs = roff[n], re = roff[n + 1];
  float dn = dis[n];
  bool act = lane < C;
  float acc = 0.f;
  for (int e = rs; e < re; e++) {
    int s = adj[e];
    float w = dis[s];
    if (act) acc += w * h[(size_t)s * C + lane];
  }
  if (act) {
    acc += dn * h[(size_t)n * C + lane];  // self loop (dis[n]^2 after outer dn)
    float v = dn * acc + bias[lane];
    out[(size_t)n * C + lane] = fmaxf(v, 0.f);
  }
}

// ---------------- pooling / head ----------------
__global__ void k_bounds(const int* __restrict__ batch, int n, int* __restrict__ gstart, int G) {
  int i = blockIdx.x * 256 + threadIdx.x;
  if (i >= n) return;
  int b = batch[i];
  if (i == 0) { for (int g = 0; g <= b; g++) gstart[g] = 0; }
  else { int p = batch[i - 1]; for (int g = p + 1; g <= b; g++) gstart[g] = i; }
  if (i == n - 1) { for (int g = b + 1; g <= G; g++) gstart[g] = n; }
}

__global__ void k_pool(const float* __restrict__ xin, const int* __restrict__ gstart,
                       float* __restrict__ pool, int C) {
  int g = blockIdx.x; int c = threadIdx.x;
  int n0 = gstart[g], n1 = gstart[g + 1];
  float m = -3.4e38f;
  for (int i = n0; i < n1; i++) m = fmaxf(m, xin[(size_t)i * C + c]);
  pool[(size_t)g * C + c] = m;
}

__global__ __launch_bounds__(64) void k_out(const float* __restrict__ t2, const float* __restrict__ w,
                                            const float* __restrict__ b, float* __restrict__ out) {
  int g = blockIdx.x, lane = threadIdx.x;
  float s = 0.f;
  for (int k = lane; k < 256; k += 64) s += t2[(size_t)g * 256 + k] * w[k];
#pragma unroll
  for (int o = 32; o; o >>= 1) s += __shfl_xor(s, o);
  if (lane == 0) out[g] = s + b[0];
}

extern "C" void kernel_launch(void* const* d_in, const int* in_sizes, int n_in,
                              void* d_out, int out_size, void* d_ws, size_t ws_size,
                              hipStream_t stream) {
  if (n_in < 28) return;
  const float* x_drug  = (const float*)d_in[0];
  const int*   ei_d    = (const int*)d_in[1];
  const int*   batch_d = (const int*)d_in[2];
  const float* x_prot  = (const float*)d_in[3];
  const int*   ei_p    = (const int*)d_in[4];
  const int*   batch_p = (const int*)d_in[5];
  const float* W1     = (const float*)d_in[6];
  const float* a_src1 = (const float*)d_in[7];
  const float* a_dst1 = (const float*)d_in[8];
  const float* b1     = (const float*)d_in[9];
  const float* W2     = (const float*)d_in[10];
  const float* a_src2 = (const float*)d_in[11];
  const float* a_dst2 = (const float*)d_in[12];
  const float* b2     = (const float*)d_in[13];
  const float* fcgW = (const float*)d_in[14];
  const float* fcgb = (const float*)d_in[15];
  const float* g1W  = (const float*)d_in[16];
  const float* g1b  = (const float*)d_in[17];
  const float* g2W  = (const float*)d_in[18];
  const float* g2b  = (const float*)d_in[19];
  const float* l1W  = (const float*)d_in[20];
  const float* l1b  = (const float*)d_in[21];
  const float* f1W  = (const float*)d_in[22];
  const float* f1b  = (const float*)d_in[23];
  const float* f2W  = (const float*)d_in[24];
  const float* f2b  = (const float*)d_in[25];
  const float* oW   = (const float*)d_in[26];
  const float* ob   = (const float*)d_in[27];

  const int nd = in_sizes[0] / 78, ed = in_sizes[1] / 2;
  const int np = in_sizes[3] / 41, ep = in_sizes[4] / 2;
  const int G = 512;

  char* Bp = (char*)d_ws;
  size_t cap = ws_size;
  auto atop = [&](size_t bytes) -> char* {
    cap = (cap - bytes) & ~(size_t)255;
    return Bp + cap;
  };
  // persistent small buffers at top of workspace
  float* pooled_d = (float*)atop((size_t)G * 128 * 4);
  float* pooled_p = (float*)atop((size_t)G * 64 * 4);
  float* xc = (float*)atop((size_t)G * 256 * 4);
  float* t1 = (float*)atop((size_t)G * 1024 * 4);
  float* t2 = (float*)atop((size_t)G * 256 * 4);
  int* gs_d = (int*)atop(513 * 4);
  int* gs_p = (int*)atop(513 * 4);

  size_t off = 0;
  auto alc = [&](size_t bytes) -> char* {
    char* p = Bp + off;
    off = (off + bytes + 255) & ~(size_t)255;
    return p;
  };

  // ================= drug branch =================
  int* cur_d  = (int*)alc((size_t)nd * 4);
  int* roff_d = (int*)alc(((size_t)nd + 1) * 4);
  int* adj_d  = (int*)alc((size_t)ed * 4);
  int* part   = (int*)alc(1024 * 4);
  int* parte  = (int*)alc(1024 * 4);
  float* Vs  = (float*)alc(780 * 4);
  float* Vd  = (float*)alc(780 * 4);
  float* al1 = (float*)alc((size_t)nd * 10 * 4);
  float* ar1 = (float*)alc((size_t)nd * 10 * 4);
  float* al2 = (float*)alc((size_t)nd * 4);
  float* ar2 = (float*)alc((size_t)nd * 4);
  float* h2  = (float*)alc((size_t)nd * 128 * 4);
  float* xd2 = (float*)alc((size_t)nd * 128 * 4);
  size_t remain = (cap > off) ? (cap - off) : 0;
  long long slabCap = (long long)(remain / (2ull * 780 * 4));
  int slabN = (int)((slabCap < (long long)nd) ? slabCap : (long long)nd);
  slabN &= ~63;
  if (slabN < 64) slabN = 64;
  float* zs   = (float*)alc((size_t)slabN * 780 * 4);
  float* xd1s = (float*)alc((size_t)slabN * 780 * 4);

  hipMemsetAsync(cur_d, 0, (size_t)nd * 4, stream);
  k_count<<<cdiv(ed, 256), 256, 0, stream>>>(ei_d + ed, ed, cur_d);
  int nch = cdiv(nd, 1024);
  k_scan_chunk<<<nch, 256, 0, stream>>>(cur_d, nd, roff_d, part);
  k_scan_chunk<<<1, 256, 0, stream>>>(part, nch, parte, nullptr);
  k_scan_add<<<cdiv(nd, 256), 256, 0, stream>>>(roff_d, nd, parte, ed, cur_d);
  k_fill<<<cdiv(ed, 256), 256, 0, stream>>>(ei_d, ei_d + ed, ed, cur_d, adj_d);

  k_vsrc<<<cdiv(780, 64), 64, 0, stream>>>(W1, a_src1, a_dst1, Vs, Vd);
  k_alar1<<<cdiv(nd * 10, 256), 256, 0, stream>>>(x_drug, Vs, Vd, al1, ar1, nd);

  for (int s0 = 0; s0 < nd; s0 += slabN) {
    int sm = ((nd - s0) < slabN) ? (nd - s0) : slabN;
    k_gat_agg1<<<sm, 64, 0, stream>>>(x_drug, adj_d, roff_d, al1, ar1, zs, s0);
    for (int h = 0; h < 10; h++)
      k_gemm<2><<<dim3(cdiv(sm, 64), 2), 256, 0, stream>>>(zs + h * 78, W1 + h * 78, b1 + h * 78,
                                                           xd1s + h * 78, sm, 78, 78, 780, 780, 780);
    k_gemm<0><<<dim3(cdiv(sm, 64), 2), 256, 0, stream>>>(xd1s, W2, nullptr, h2 + (size_t)s0 * 128,
                                                         sm, 128, 780, 780, 128, 128);
  }
  k_alar2<<<nd, 64, 0, stream>>>(h2, a_src2, a_dst2, al2, ar2);
  k_gat_agg2<<<nd, 64, 0, stream>>>(h2, adj_d, roff_d, al2, ar2, b2, xd2);
  k_bounds<<<cdiv(nd, 256), 256, 0, stream>>>(batch_d, nd, gs_d, G);
  k_pool<<<G, 128, 0, stream>>>(xd2, gs_d, pooled_d, 128);
  k_gemm<1><<<dim3(cdiv(G, 64), 2), 256, 0, stream>>>(pooled_d, fcgW, fcgb, xc, G, 128, 128, 128, 128, 256);

  // ================= protein branch (overlays drug pool; stream-ordered) =================
  off = 0;
  int* cur_p  = (int*)alc((size_t)np * 4);
  int* roff_p = (int*)alc(((size_t)np + 1) * 4);
  int* adj_p  = (int*)alc((size_t)ep * 4);
  int* partp  = (int*)alc(1024 * 4);
  int* partep = (int*)alc(1024 * 4);
  float* dis = (float*)alc((size_t)np * 4);
  float* hp1 = (float*)alc((size_t)np * 41 * 4);
  float* xp1 = (float*)alc((size_t)np * 41 * 4);
  float* hp2 = (float*)alc((size_t)np * 64 * 4);
  float* xp2 = hp1;  // hp1 dead by the time xp2 is written

  hipMemsetAsync(cur_p, 0, (size_t)np * 4, stream);
  k_count<<<cdiv(ep, 256), 256, 0, stream>>>(ei_p + ep, ep, cur_p);
  int nchp = cdiv(np, 1024);
  k_scan_chunk<<<nchp, 256, 0, stream>>>(cur_p, np, roff_p, partp);
  k_scan_chunk<<<1, 256, 0, stream>>>(partp, nchp, partep, nullptr);
  k_scan_add<<<cdiv(np, 256), 256, 0, stream>>>(roff_p, np, partep, ep, cur_p);
  k_fill<<<cdiv(ep, 256), 256, 0, stream>>>(ei_p, ei_p + ep, ep, cur_p, adj_p);
  k_dis<<<cdiv(np, 256), 256, 0, stream>>>(roff_p, dis, np);

  k_gemm<0><<<dim3(cdiv(np, 64), 1), 256, 0, stream>>>(x_prot, g1W, nullptr, hp1, np, 41, 41, 41, 41, 41);
  k_gcn_agg<<<np, 64, 0, stream>>>(hp1, adj_p, roff_p, dis, g1b, xp1, 41);
  k_gemm<0><<<dim3(cdiv(np, 64), 1), 256, 0, stream>>>(xp1, g2W, nullptr, hp2, np, 64, 41, 41, 64, 64);
  k_gcn_agg<<<np, 64, 0, stream>>>(hp2, adj_p, roff_p, dis, g2b, xp2, 64);
  k_bounds<<<cdiv(np, 256), 256, 0, stream>>>(batch_p, np, gs_p, G);
  k_pool<<<G, 64, 0, stream>>>(xp2, gs_p, pooled_p, 64);
  k_gemm<1><<<dim3(cdiv(G, 64), 2), 256, 0, stream>>>(pooled_p, l1W, l1b, xc + 128, G, 128, 64, 64, 128, 256);

  // ================= head =================
  k_gemm<1><<<dim3(cdiv(G, 64), 16), 256, 0, stream>>>(xc, f1W, f1b, t1, G, 1024, 256, 256, 1024, 1024);
  k_gemm<1><<<dim3(cdiv(G, 64), 4), 256, 0, stream>>>(t1, f2W, f2b, t2, G, 256, 1024, 1024, 256, 256);
  k_out<<<G, 64, 0, stream>>>(t2, oW, ob, (float*)d_out);
}